// Round 6
// baseline (204.261 us; speedup 1.0000x reference)
//
#include <hip/hip_runtime.h>
#include <hip/hip_bf16.h>

#define SEQ 2048
#define BHCOUNT 32
#define NROWS (BHCOUNT*SEQ)   /* 65536 rows of [64] */

typedef unsigned short u16;
typedef unsigned int u32;
using bf16x8 = __attribute__((ext_vector_type(8))) short;   // 8 bf16 = 4 VGPR
using f32x4  = __attribute__((ext_vector_type(4))) float;

__device__ __forceinline__ float bf2f(u16 h) {
    return __uint_as_float(((u32)h) << 16);
}
__device__ __forceinline__ u16 f2bf(float f) {
    u32 u = __float_as_uint(f);
    u32 r = (u + 0x7FFFu + ((u >> 16) & 1u)) >> 16;
    return (u16)r;
}

// ---------------------------------------------------------------------------
// Kernel 1: QKV projection.  x[65536][64] fp32 ->
//   Q bf16 [65536][64]  (pre-scaled by 0.125*log2e for exp2-domain softmax)
//   K bf16 [65536][64]
//   Vg bf16 [32 bh][32 kv-tile][64 d][64 kappa]  — kappa-permuted V tiles so
//   attention's PV B-fragments match the in-register P packing:
//     kappa = 32*(nt&1) + 8*g4 + 4*(nt>>1) + r,  kv = 16*nt + 4*g4 + r
//     (kv bits: [5]=kappa[2], [4]=kappa[5], [3:2]=kappa[4:3], [1:0]=kappa[1:0])
// ---------------------------------------------------------------------------
__global__ __launch_bounds__(256) void qkv_kernel(
    const float* __restrict__ x,
    const float* __restrict__ wq, const float* __restrict__ bq,
    const float* __restrict__ wk, const float* __restrict__ bk,
    const float* __restrict__ wv, const float* __restrict__ bv,
    u16* __restrict__ Q, u16* __restrict__ K, u16* __restrict__ Vg)
{
    __shared__ float wqs[64*68], wks[64*68], wvs[64*68];
    __shared__ float xs[64*64];
    __shared__ float bqs[64], bks[64], bvs[64];
    const int t = threadIdx.x;

    for (int i = t*4; i < 4096; i += 1024) {
        int r = i >> 6, c = i & 63;
        *(float4*)&wqs[r*68+c] = *(const float4*)&wq[i];
        *(float4*)&wks[r*68+c] = *(const float4*)&wk[i];
        *(float4*)&wvs[r*68+c] = *(const float4*)&wv[i];
        *(float4*)&xs[i] = *(const float4*)&x[(size_t)blockIdx.x*4096 + i];
    }
    if (t < 64) { bqs[t] = bq[t]; bks[t] = bk[t]; bvs[t] = bv[t]; }
    __syncthreads();

    const int e = t & 63, wg = t >> 6;
    const int bh = blockIdx.x >> 5;          // 64 rows/block, 32 blocks per bh
    const float qscale = 0.125f * 1.44269504f;
    float va[16];

    #pragma unroll
    for (int g = 0; g < 2; ++g) {
        const int r0 = wg*16 + g*8;
        float aq[8], ak[8], av[8];
        #pragma unroll
        for (int i = 0; i < 8; ++i) { aq[i] = bqs[e]; ak[i] = bks[e]; av[i] = bvs[e]; }
        for (int ds = 0; ds < 16; ++ds) {
            float4 q4 = *(const float4*)&wqs[e*68 + ds*4];
            float4 k4 = *(const float4*)&wks[e*68 + ds*4];
            float4 v4 = *(const float4*)&wvs[e*68 + ds*4];
            #pragma unroll
            for (int i = 0; i < 8; ++i) {
                float4 xv = *(const float4*)&xs[(r0+i)*64 + ds*4];
                aq[i] += xv.x*q4.x + xv.y*q4.y + xv.z*q4.z + xv.w*q4.w;
                ak[i] += xv.x*k4.x + xv.y*k4.y + xv.z*k4.z + xv.w*k4.w;
                av[i] += xv.x*v4.x + xv.y*v4.y + xv.z*v4.z + xv.w*v4.w;
            }
        }
        #pragma unroll
        for (int i = 0; i < 8; ++i) {
            size_t row = (size_t)blockIdx.x*64 + r0 + i;
            Q[row*64 + e] = f2bf(aq[i]*qscale);
            K[row*64 + e] = f2bf(ak[i]);
            va[g*8+i] = av[i];
        }
    }

    // transpose V through xs (rotated layout keeps LDS banks conflict-free)
    __syncthreads();
    #pragma unroll
    for (int g = 0; g < 2; ++g)
        #pragma unroll
        for (int i = 0; i < 8; ++i) {
            int r = wg*16 + g*8 + i;
            xs[e*64 + ((r + e) & 63)] = va[g*8+i];
        }
    __syncthreads();
    // write kappa-permuted tile: Vg[bh][kt][d=ee][kappa]
    const size_t vgbase = ((size_t)bh*32 + (blockIdx.x & 31)) * 4096;
    for (int idx = t; idx < 4096; idx += 256) {
        int ee = idx >> 6, kp = idx & 63;
        int s = ((kp & 4) << 3) | ((kp & 32) >> 1) | ((kp & 24) >> 1) | (kp & 3);
        Vg[vgbase + idx] = f2bf(xs[ee*64 + ((s + ee) & 63)]);
    }
}

// ---------------------------------------------------------------------------
// Kernel 2: MFMA flash attention, swapped-QK^T (P stays in registers).
// grid (32 qtiles, 32 bh); 4 waves, each wave owns 16 q-rows; kv-tile = 64.
// QK^T: sacc[nt] = mfma(K_frag, Q_frag)  ->  lane (ln,g4) holds
//   S[q=ln][kv = nt*16 + g4*4 + r]  — a full q-row per lane, so softmax
//   reductions are in-register + 2 shfl_xor(16,32) across the g4 group.
// P is packed in-register via v_cvt_pk_bf16_f32 into PV A-frags with
//   kappa = kf*32 + g4*8 + j,  j = 4*(nt>>1)+r, kf = nt&1  (matches Vg).
// PV: oacc[dt] = mfma(pf, V_frag) -> O[q=g4*4+r][d=dt*16+ln]; rescale alphas
// for q'=4*g4+r gathered from lane 20*g4+r by shfl.
// C/D layout (HW-verified): col=lane&15, row=(lane>>4)*4+reg.
// ---------------------------------------------------------------------------
__global__ __launch_bounds__(256) void attn_kernel(
    const u16* __restrict__ Q, const u16* __restrict__ K,
    const u16* __restrict__ Vg, u16* __restrict__ ctx)
{
    __shared__ u16 Ks [64*64];       // [kv][d], swizzled
    __shared__ u16 Vts[64*64];       // [d][kappa], swizzled

    const int t = threadIdx.x;
    const int wid = t >> 6, lane = t & 63;
    const int ln = lane & 15, g4 = lane >> 4;
    const int bh = blockIdx.y;
    const size_t base = (size_t)bh * SEQ * 64;
    const int q0 = blockIdx.x * 64 + wid * 16;

    // Q fragments (B-operand of swapped QK^T): lane holds Q[q0+ln][kf*32+g4*8+j]
    bf16x8 qf[2];
    #pragma unroll
    for (int kf = 0; kf < 2; ++kf)
        qf[kf] = *(const bf16x8*)&Q[base + (size_t)(q0 + ln)*64 + kf*32 + g4*8];

    f32x4 oacc[4];
    #pragma unroll
    for (int i = 0; i < 4; ++i) oacc[i] = (f32x4){0.f, 0.f, 0.f, 0.f};
    float m = -1e30f, l = 0.f;     // softmax state for q = ln (lane-local row)

    // prologue: preload tile 0 into registers (T14-lite pipeline)
    uint4 kreg[2], vreg[2];
    {
        const u16* ksrc = &K[base];
        const u16* vsrc = &Vg[(size_t)bh * 32 * 4096];
        #pragma unroll
        for (int c = 0; c < 2; ++c) {
            int s = t + c*256;
            kreg[c] = *(const uint4*)&ksrc[s*8];
            vreg[c] = *(const uint4*)&vsrc[s*8];
        }
    }

    for (int kt = 0; kt < 32; ++kt) {
        __syncthreads();   // previous tile's LDS reads complete
        #pragma unroll
        for (int c = 0; c < 2; ++c) {
            int s = t + c*256;                 // 512 slots of 16B per tile
            int row = s >> 3, ks = s & 7;
            int phys = row*64 + ((ks ^ (row & 7)) << 3);
            *(uint4*)&Ks [phys] = kreg[c];
            *(uint4*)&Vts[phys] = vreg[c];
        }
        {   // issue next tile's loads; they land during this tile's compute
            int ktn = (kt < 31) ? kt + 1 : 31;
            const u16* ksrc = &K[base + (size_t)ktn*4096];
            const u16* vsrc = &Vg[((size_t)bh*32 + ktn) * 4096];
            #pragma unroll
            for (int c = 0; c < 2; ++c) {
                int s = t + c*256;
                kreg[c] = *(const uint4*)&ksrc[s*8];
                vreg[c] = *(const uint4*)&vsrc[s*8];
            }
        }
        __syncthreads();

        // S^T tiles: sacc[nt] = K_tile(nt) · Q^T
        f32x4 sacc[4];
        #pragma unroll
        for (int nt = 0; nt < 4; ++nt) sacc[nt] = (f32x4){0.f, 0.f, 0.f, 0.f};
        #pragma unroll
        for (int nt = 0; nt < 4; ++nt) {
            #pragma unroll
            for (int kf = 0; kf < 2; ++kf) {
                int krow = nt*16 + ln;
                bf16x8 kfr = *(const bf16x8*)&Ks[krow*64 + (((kf*4 + g4) ^ (krow & 7)) << 3)];
                sacc[nt] = __builtin_amdgcn_mfma_f32_16x16x32_bf16(kfr, qf[kf], sacc[nt], 0, 0, 0);
            }
        }

        // lane-local online softmax for q = ln (16 values in-register)
        float mx = fmaxf(
            fmaxf(fmaxf(fmaxf(sacc[0][0], sacc[0][1]), fmaxf(sacc[0][2], sacc[0][3])),
                  fmaxf(fmaxf(sacc[1][0], sacc[1][1]), fmaxf(sacc[1][2], sacc[1][3]))),
            fmaxf(fmaxf(fmaxf(sacc[2][0], sacc[2][1]), fmaxf(sacc[2][2], sacc[2][3])),
                  fmaxf(fmaxf(sacc[3][0], sacc[3][1]), fmaxf(sacc[3][2], sacc[3][3]))));
        mx = fmaxf(mx, __shfl_xor(mx, 16));
        mx = fmaxf(mx, __shfl_xor(mx, 32));
        float mn = fmaxf(m, mx);
        float alpha = exp2f(m - mn);
        m = mn;
        float rs = 0.f;
        #pragma unroll
        for (int nt = 0; nt < 4; ++nt)
            #pragma unroll
            for (int r = 0; r < 4; ++r) {
                sacc[nt][r] = exp2f(sacc[nt][r] - mn);   // p in place
                rs += sacc[nt][r];
            }
        rs += __shfl_xor(rs, 16);
        rs += __shfl_xor(rs, 32);
        l = l*alpha + rs;

        // rescale oacc rows (q' = 4*g4 + r): gather alpha from lane 20*g4+r
        #pragma unroll
        for (int r = 0; r < 4; ++r) {
            float ar = __shfl(alpha, 20*g4 + r);
            #pragma unroll
            for (int dt = 0; dt < 4; ++dt) oacc[dt][r] *= ar;
        }

        // pack P into PV A-frags: pf[kf] = [p[kf][0..3], p[kf+2][0..3]]
        union PU { u32 w[4]; bf16x8 v; } pu0, pu1;
        asm("v_cvt_pk_bf16_f32 %0, %1, %2" : "=v"(pu0.w[0]) : "v"(sacc[0][0]), "v"(sacc[0][1]));
        asm("v_cvt_pk_bf16_f32 %0, %1, %2" : "=v"(pu0.w[1]) : "v"(sacc[0][2]), "v"(sacc[0][3]));
        asm("v_cvt_pk_bf16_f32 %0, %1, %2" : "=v"(pu0.w[2]) : "v"(sacc[2][0]), "v"(sacc[2][1]));
        asm("v_cvt_pk_bf16_f32 %0, %1, %2" : "=v"(pu0.w[3]) : "v"(sacc[2][2]), "v"(sacc[2][3]));
        asm("v_cvt_pk_bf16_f32 %0, %1, %2" : "=v"(pu1.w[0]) : "v"(sacc[1][0]), "v"(sacc[1][1]));
        asm("v_cvt_pk_bf16_f32 %0, %1, %2" : "=v"(pu1.w[1]) : "v"(sacc[1][2]), "v"(sacc[1][3]));
        asm("v_cvt_pk_bf16_f32 %0, %1, %2" : "=v"(pu1.w[2]) : "v"(sacc[3][0]), "v"(sacc[3][1]));
        asm("v_cvt_pk_bf16_f32 %0, %1, %2" : "=v"(pu1.w[3]) : "v"(sacc[3][2]), "v"(sacc[3][3]));
        bf16x8 pf[2] = { pu0.v, pu1.v };

        // O += P · V'
        #pragma unroll
        for (int dt = 0; dt < 4; ++dt) {
            #pragma unroll
            for (int kf = 0; kf < 2; ++kf) {
                int vrow = dt*16 + ln;
                bf16x8 vfr = *(const bf16x8*)&Vts[vrow*64 + (((kf*4 + g4) ^ (vrow & 7)) << 3)];
                oacc[dt] = __builtin_amdgcn_mfma_f32_16x16x32_bf16(pf[kf], vfr, oacc[dt], 0, 0, 0);
            }
        }
    }

    // epilogue: normalize rows q' = 4*g4+r (l gathered from lane 20*g4+r)
    #pragma unroll
    for (int r = 0; r < 4; ++r) {
        float inv = 1.f / __shfl(l, 20*g4 + r);
        size_t row = base + (size_t)(q0 + g4*4 + r)*64;
        #pragma unroll
        for (int dt = 0; dt < 4; ++dt)
            ctx[row + dt*16 + ln] = f2bf(oacc[dt][r] * inv);
    }
}

// ---------------------------------------------------------------------------
// Kernel 3a: convert wo fp32 [1024][1024] -> bf16 tiled
//   wob_t[cb][kt][row][k] = wo[cb*64+row][kt*64+k]   (tile = contiguous 4096)
// ---------------------------------------------------------------------------
__global__ __launch_bounds__(256) void wconv_kernel(
    const float* __restrict__ wo, u16* __restrict__ wob_t)
{
    int g = blockIdx.x*256 + threadIdx.x;   // 131072 slots of 8 elems
    int tile = g >> 9, within = g & 511;
    int row = within >> 3, ks = within & 7;
    int cb = tile >> 4, kt = tile & 15;
    const float* src = &wo[(size_t)(cb*64 + row)*1024 + kt*64 + ks*8];
    float4 a = *(const float4*)src;
    float4 b = *(const float4*)(src + 4);
    u16 o[8];
    o[0]=f2bf(a.x); o[1]=f2bf(a.y); o[2]=f2bf(a.z); o[3]=f2bf(a.w);
    o[4]=f2bf(b.x); o[5]=f2bf(b.y); o[6]=f2bf(b.z); o[7]=f2bf(b.w);
    *(uint4*)&wob_t[(size_t)g*8] = *(uint4*)o;
}

// ---------------------------------------------------------------------------
// Kernel 3b: MFMA output projection.
//   out[m][n] = sum_k A[m][k] * wo[n][k] + bo[n],  M=4096, N=K=1024
// A = ctx workspace reinterpreted as flat row-major [4096][1024] (the
// reference's reshape is a plain flat reshape — round-4 lesson).
// ---------------------------------------------------------------------------
__global__ __launch_bounds__(256) void oproj_kernel(
    const u16* __restrict__ ctx, const u16* __restrict__ wob_t,
    const float* __restrict__ bo, float* __restrict__ out)
{
    __shared__ u16 As[128*64];   // [m][k], swizzled
    __shared__ u16 Bs[64*64];    // [n][k], swizzled
    const int t = threadIdx.x;
    const int wid = t >> 6, lane = t & 63;
    const int ln = lane & 15, g4 = lane >> 4;
    const int wr = wid >> 1, wc = wid & 1;
    const int rb = blockIdx.x, cb = blockIdx.y;
    const int m0 = rb * 128;

    f32x4 acc[4][2];
    #pragma unroll
    for (int mf = 0; mf < 4; ++mf)
        #pragma unroll
        for (int nf = 0; nf < 2; ++nf)
            acc[mf][nf] = (f32x4){0.f, 0.f, 0.f, 0.f};

    for (int kt = 0; kt < 16; ++kt) {
        const u16* bsrc = &wob_t[(size_t)(cb*16 + kt) * 4096];
        __syncthreads();
        #pragma unroll
        for (int c = 0; c < 4; ++c) {
            int sA = t + c*256;                  // 1024 slots of 16B
            int row = sA >> 3, ks = sA & 7;
            *(uint4*)&As[row*64 + ((ks ^ (row & 7)) << 3)] =
                *(const uint4*)&ctx[(size_t)(m0 + row)*1024 + kt*64 + ks*8];
        }
        #pragma unroll
        for (int c = 0; c < 2; ++c) {
            int sB = t + c*256;                  // 512 slots of 16B
            int row = sB >> 3, ks = sB & 7;
            *(uint4*)&Bs[row*64 + ((ks ^ (row & 7)) << 3)] = *(const uint4*)&bsrc[sB*8];
        }
        __syncthreads();

        #pragma unroll
        for (int kf = 0; kf < 2; ++kf) {
            bf16x8 af[4], bfr[2];
            #pragma unroll
            for (int mf = 0; mf < 4; ++mf) {
                int arow = wr*64 + mf*16 + ln;
                af[mf] = *(const bf16x8*)&As[arow*64 + (((kf*4 + g4) ^ (arow & 7)) << 3)];
            }
            #pragma unroll
            for (int nf = 0; nf < 2; ++nf) {
                int brow = wc*32 + nf*16 + ln;
                bfr[nf] = *(const bf16x8*)&Bs[brow*64 + (((kf*4 + g4) ^ (brow & 7)) << 3)];
            }
            #pragma unroll
            for (int mf = 0; mf < 4; ++mf)
                #pragma unroll
                for (int nf = 0; nf < 2; ++nf)
                    acc[mf][nf] = __builtin_amdgcn_mfma_f32_16x16x32_bf16(af[mf], bfr[nf], acc[mf][nf], 0, 0, 0);
        }
    }

    #pragma unroll
    for (int mf = 0; mf < 4; ++mf)
        #pragma unroll
        for (int r = 0; r < 4; ++r) {
            int m = m0 + wr*64 + mf*16 + g4*4 + r;
            #pragma unroll
            for (int nf = 0; nf < 2; ++nf) {
                int col = cb*64 + wc*32 + nf*16 + ln;
                out[(size_t)m*1024 + col] = acc[mf][nf][r] + bo[col];
            }
        }
}

extern "C" void kernel_launch(void* const* d_in, const int* in_sizes, int n_in,
                              void* d_out, int out_size, void* d_ws, size_t ws_size,
                              hipStream_t stream) {
    (void)in_sizes; (void)n_in; (void)out_size; (void)ws_size;
    const float* x  = (const float*)d_in[0];
    const float* wq = (const float*)d_in[1];
    const float* bq = (const float*)d_in[2];
    const float* wk = (const float*)d_in[3];
    const float* bk = (const float*)d_in[4];
    const float* wv = (const float*)d_in[5];
    const float* bv = (const float*)d_in[6];
    const float* wo = (const float*)d_in[7];
    const float* bo = (const float*)d_in[8];
    float* out = (float*)d_out;

    // workspace: Q,K bf16 [65536][64]; Vg bf16 [32][32][64][64]; ctx -> 32 MB
    // After attn_kernel, Q is dead -> its region hosts wob_t (2 MB of 8 MB).
    u16* Qb  = (u16*)d_ws;
    u16* Kb  = Qb + (size_t)NROWS*64;
    u16* Vgb = Kb + (size_t)NROWS*64;
    u16* ctx = Vgb + (size_t)NROWS*64;
    u16* wob_t = Qb;

    qkv_kernel<<<dim3(NROWS/64), 256, 0, stream>>>(x, wq, bq, wk, bk, wv, bv, Qb, Kb, Vgb);
    attn_kernel<<<dim3(32, 32), 256, 0, stream>>>(Qb, Kb, Vgb, ctx);
    wconv_kernel<<<dim3(512), 256, 0, stream>>>(wo, wob_t);
    oproj_kernel<<<dim3(32, 16), 256, 0, stream>>>(ctx, wob_t, bo, out);
}

// Round 7
// 134.196 us; speedup vs baseline: 1.5221x; 1.5221x over previous
//
#include <hip/hip_runtime.h>
#include <hip/hip_bf16.h>

#define SEQ 2048
#define BHCOUNT 32
#define NROWS (BHCOUNT*SEQ)   /* 65536 rows of [64] */

typedef unsigned short u16;
typedef unsigned int u32;
using bf16x8 = __attribute__((ext_vector_type(8))) short;   // 8 bf16 = 4 VGPR
using f32x4  = __attribute__((ext_vector_type(4))) float;

__device__ __forceinline__ float bf2f(u16 h) {
    return __uint_as_float(((u32)h) << 16);
}
__device__ __forceinline__ u16 f2bf(float f) {
    u32 u = __float_as_uint(f);
    u32 r = (u + 0x7FFFu + ((u >> 16) & 1u)) >> 16;
    return (u16)r;
}

// async global->LDS, 16B per lane. Global addr is PER-LANE, LDS dest is
// wave-uniform base + lane*16 (m104). Size must be a literal.
__device__ __forceinline__ void gload16(const u16* g, u16* l) {
    __builtin_amdgcn_global_load_lds(
        (const __attribute__((address_space(1))) u32*)g,
        (__attribute__((address_space(3))) u32*)l, 16, 0, 0);
}

// ---------------------------------------------------------------------------
// Kernel 1: QKV projection.  x[65536][64] fp32 ->
//   Q bf16 [65536][64]  (pre-scaled by 0.125*log2e for exp2-domain softmax)
//   K bf16 [65536][64]
//   Vg bf16 [32 bh][32 kv-tile][64 d][64 kappa]  — kappa-permuted V tiles so
//   attention's PV B-fragments match the in-register P packing:
//     kappa = 32*(nt&1) + 8*g4 + 4*(nt>>1) + r,  kv = 16*nt + 4*g4 + r
// ---------------------------------------------------------------------------
__global__ __launch_bounds__(256) void qkv_kernel(
    const float* __restrict__ x,
    const float* __restrict__ wq, const float* __restrict__ bq,
    const float* __restrict__ wk, const float* __restrict__ bk,
    const float* __restrict__ wv, const float* __restrict__ bv,
    u16* __restrict__ Q, u16* __restrict__ K, u16* __restrict__ Vg)
{
    __shared__ float wqs[64*68], wks[64*68], wvs[64*68];
    __shared__ float xs[64*64];
    __shared__ float bqs[64], bks[64], bvs[64];
    const int t = threadIdx.x;

    for (int i = t*4; i < 4096; i += 1024) {
        int r = i >> 6, c = i & 63;
        *(float4*)&wqs[r*68+c] = *(const float4*)&wq[i];
        *(float4*)&wks[r*68+c] = *(const float4*)&wk[i];
        *(float4*)&wvs[r*68+c] = *(const float4*)&wv[i];
        *(float4*)&xs[i] = *(const float4*)&x[(size_t)blockIdx.x*4096 + i];
    }
    if (t < 64) { bqs[t] = bq[t]; bks[t] = bk[t]; bvs[t] = bv[t]; }
    __syncthreads();

    const int e = t & 63, wg = t >> 6;
    const int bh = blockIdx.x >> 5;          // 64 rows/block, 32 blocks per bh
    const float qscale = 0.125f * 1.44269504f;
    float va[16];

    #pragma unroll
    for (int g = 0; g < 2; ++g) {
        const int r0 = wg*16 + g*8;
        float aq[8], ak[8], av[8];
        #pragma unroll
        for (int i = 0; i < 8; ++i) { aq[i] = bqs[e]; ak[i] = bks[e]; av[i] = bvs[e]; }
        for (int ds = 0; ds < 16; ++ds) {
            float4 q4 = *(const float4*)&wqs[e*68 + ds*4];
            float4 k4 = *(const float4*)&wks[e*68 + ds*4];
            float4 v4 = *(const float4*)&wvs[e*68 + ds*4];
            #pragma unroll
            for (int i = 0; i < 8; ++i) {
                float4 xv = *(const float4*)&xs[(r0+i)*64 + ds*4];
                aq[i] += xv.x*q4.x + xv.y*q4.y + xv.z*q4.z + xv.w*q4.w;
                ak[i] += xv.x*k4.x + xv.y*k4.y + xv.z*k4.z + xv.w*k4.w;
                av[i] += xv.x*v4.x + xv.y*v4.y + xv.z*v4.z + xv.w*v4.w;
            }
        }
        #pragma unroll
        for (int i = 0; i < 8; ++i) {
            size_t row = (size_t)blockIdx.x*64 + r0 + i;
            Q[row*64 + e] = f2bf(aq[i]*qscale);
            K[row*64 + e] = f2bf(ak[i]);
            va[g*8+i] = av[i];
        }
    }

    // transpose V through xs (rotated layout keeps LDS banks conflict-free)
    __syncthreads();
    #pragma unroll
    for (int g = 0; g < 2; ++g)
        #pragma unroll
        for (int i = 0; i < 8; ++i) {
            int r = wg*16 + g*8 + i;
            xs[e*64 + ((r + e) & 63)] = va[g*8+i];
        }
    __syncthreads();
    // write kappa-permuted tile: Vg[bh][kt][d=ee][kappa]
    const size_t vgbase = ((size_t)bh*32 + (blockIdx.x & 31)) * 4096;
    for (int idx = t; idx < 4096; idx += 256) {
        int ee = idx >> 6, kp = idx & 63;
        int s = ((kp & 4) << 3) | ((kp & 32) >> 1) | ((kp & 24) >> 1) | (kp & 3);
        Vg[vgbase + idx] = f2bf(xs[ee*64 + ((s + ee) & 63)]);
    }
}

// ---------------------------------------------------------------------------
// Kernel 2: MFMA flash attention, swapped-QK^T, async double-buffered staging.
// grid (32 qtiles, 32 bh); 4 waves; kv-tile = 64.
// Staging (T3 minimum-2-phase): issue tile kt+1 via global_load_lds into
// buf^1 BEFORE computing tile kt from buf; ONE __syncthreads per iteration
// (compiler's vmcnt(0) before the barrier drains loads that overlapped the
// whole compute phase). LDS swizzle achieved by pre-swizzling the per-lane
// GLOBAL source address (XOR involution), LDS dest linear (m104/m173).
// QK^T swapped: sacc[nt] = mfma(K_frag, Q_frag) -> lane (ln,g4) holds
// S[q=ln][kv=nt*16+g4*4+r] — full q-row per lane; softmax needs only 2
// shfl_xor. P packed in-register (v_cvt_pk_bf16_f32) into PV A-frags
// matching the kappa-permuted Vg. Defer-max (T13, THR=8 in exp2 domain):
// rescale branch (alpha broadcast + oacc scaling) skipped unless
// __any(mx - m > 8) — essentially always skipped for this data.
// C/D layout (HW-verified): col=lane&15, row=(lane>>4)*4+reg.
// ---------------------------------------------------------------------------
__global__ __launch_bounds__(256) void attn_kernel(
    const u16* __restrict__ Q, const u16* __restrict__ K,
    const u16* __restrict__ Vg, u16* __restrict__ ctx)
{
    __shared__ u16 Kls[2][64*64];    // [buf][phys], swizzled via source
    __shared__ u16 Vls[2][64*64];

    const int t = threadIdx.x;
    const int wid = t >> 6, lane = t & 63;
    const int ln = lane & 15, g4 = lane >> 4;
    const int bh = blockIdx.y;
    const size_t base   = (size_t)bh * SEQ * 64;
    const size_t vgbase = (size_t)bh * 32 * 4096;
    const int q0 = blockIdx.x * 64 + wid * 16;

    // per-lane swizzled source offsets for the 2 chunks this wave stages:
    // phys slot s = wid*128 + c*64 + lane holds logical (row, ks^(row&7))
    int goff[2];
    #pragma unroll
    for (int c = 0; c < 2; ++c) {
        int s = wid*128 + c*64 + lane;
        int row = s >> 3, ks = s & 7;
        goff[c] = row*64 + ((ks ^ (row & 7)) << 3);
    }
    const int ldst = wid*128*8;   // element offset of this wave's LDS region

    // Q fragments (B-operand of swapped QK^T): lane holds Q[q0+ln][kf*32+g4*8+j]
    bf16x8 qf[2];
    #pragma unroll
    for (int kf = 0; kf < 2; ++kf)
        qf[kf] = *(const bf16x8*)&Q[base + (size_t)(q0 + ln)*64 + kf*32 + g4*8];

    f32x4 oacc[4];
    #pragma unroll
    for (int i = 0; i < 4; ++i) oacc[i] = (f32x4){0.f, 0.f, 0.f, 0.f};
    float m = -1e30f, l = 0.f;     // softmax state for q = ln (lane-local row)

    // prologue: stage tile 0 into buf 0
    #pragma unroll
    for (int c = 0; c < 2; ++c) {
        gload16(&K [base   + goff[c]], &Kls[0][ldst + c*512]);
        gload16(&Vg[vgbase + goff[c]], &Vls[0][ldst + c*512]);
    }
    __syncthreads();   // vmcnt(0) drain + publish tile 0

    for (int kt = 0; kt < 32; ++kt) {
        const int cur = kt & 1;
        if (kt < 31) {   // issue next tile's async loads into the other buffer
            const u16* ksrc = &K [base   + (size_t)(kt+1)*4096];
            const u16* vsrc = &Vg[vgbase + (size_t)(kt+1)*4096];
            #pragma unroll
            for (int c = 0; c < 2; ++c) {
                gload16(&ksrc[goff[c]], &Kls[cur^1][ldst + c*512]);
                gload16(&vsrc[goff[c]], &Vls[cur^1][ldst + c*512]);
            }
        }
        const u16* Ks  = Kls[cur];
        const u16* Vts = Vls[cur];

        // S^T tiles: sacc[nt] = K_tile(nt) · Q^T
        f32x4 sacc[4];
        #pragma unroll
        for (int nt = 0; nt < 4; ++nt) sacc[nt] = (f32x4){0.f, 0.f, 0.f, 0.f};
        #pragma unroll
        for (int nt = 0; nt < 4; ++nt) {
            #pragma unroll
            for (int kf = 0; kf < 2; ++kf) {
                int krow = nt*16 + ln;
                bf16x8 kfr = *(const bf16x8*)&Ks[krow*64 + (((kf*4 + g4) ^ (krow & 7)) << 3)];
                sacc[nt] = __builtin_amdgcn_mfma_f32_16x16x32_bf16(kfr, qf[kf], sacc[nt], 0, 0, 0);
            }
        }

        // lane-local online softmax for q = ln (16 values in-register)
        float mx = fmaxf(
            fmaxf(fmaxf(fmaxf(sacc[0][0], sacc[0][1]), fmaxf(sacc[0][2], sacc[0][3])),
                  fmaxf(fmaxf(sacc[1][0], sacc[1][1]), fmaxf(sacc[1][2], sacc[1][3]))),
            fmaxf(fmaxf(fmaxf(sacc[2][0], sacc[2][1]), fmaxf(sacc[2][2], sacc[2][3])),
                  fmaxf(fmaxf(sacc[3][0], sacc[3][1]), fmaxf(sacc[3][2], sacc[3][3]))));
        mx = fmaxf(mx, __shfl_xor(mx, 16));
        mx = fmaxf(mx, __shfl_xor(mx, 32));

        // defer-max (T13): rescale only when some row's max grew past THR=8
        float alpha = 1.f;
        if (__any(mx - m > 8.f)) {
            float mn = fmaxf(m, mx);
            alpha = exp2f(m - mn);
            m = mn;
            #pragma unroll
            for (int r = 0; r < 4; ++r) {
                float ar = __shfl(alpha, 20*g4 + r);
                #pragma unroll
                for (int dt = 0; dt < 4; ++dt) oacc[dt][r] *= ar;
            }
        }

        float rs = 0.f;
        #pragma unroll
        for (int nt = 0; nt < 4; ++nt)
            #pragma unroll
            for (int r = 0; r < 4; ++r) {
                sacc[nt][r] = exp2f(sacc[nt][r] - m);   // p in place (<= 2^8)
                rs += sacc[nt][r];
            }
        rs += __shfl_xor(rs, 16);
        rs += __shfl_xor(rs, 32);
        l = l*alpha + rs;

        // pack P into PV A-frags: pf[kf] = [p[kf][0..3], p[kf+2][0..3]]
        union PU { u32 w[4]; bf16x8 v; } pu0, pu1;
        asm("v_cvt_pk_bf16_f32 %0, %1, %2" : "=v"(pu0.w[0]) : "v"(sacc[0][0]), "v"(sacc[0][1]));
        asm("v_cvt_pk_bf16_f32 %0, %1, %2" : "=v"(pu0.w[1]) : "v"(sacc[0][2]), "v"(sacc[0][3]));
        asm("v_cvt_pk_bf16_f32 %0, %1, %2" : "=v"(pu0.w[2]) : "v"(sacc[2][0]), "v"(sacc[2][1]));
        asm("v_cvt_pk_bf16_f32 %0, %1, %2" : "=v"(pu0.w[3]) : "v"(sacc[2][2]), "v"(sacc[2][3]));
        asm("v_cvt_pk_bf16_f32 %0, %1, %2" : "=v"(pu1.w[0]) : "v"(sacc[1][0]), "v"(sacc[1][1]));
        asm("v_cvt_pk_bf16_f32 %0, %1, %2" : "=v"(pu1.w[1]) : "v"(sacc[1][2]), "v"(sacc[1][3]));
        asm("v_cvt_pk_bf16_f32 %0, %1, %2" : "=v"(pu1.w[2]) : "v"(sacc[3][0]), "v"(sacc[3][1]));
        asm("v_cvt_pk_bf16_f32 %0, %1, %2" : "=v"(pu1.w[3]) : "v"(sacc[3][2]), "v"(sacc[3][3]));
        bf16x8 pf[2] = { pu0.v, pu1.v };

        // O += P · V'
        #pragma unroll
        for (int dt = 0; dt < 4; ++dt) {
            #pragma unroll
            for (int kf = 0; kf < 2; ++kf) {
                int vrow = dt*16 + ln;
                bf16x8 vfr = *(const bf16x8*)&Vts[vrow*64 + (((kf*4 + g4) ^ (vrow & 7)) << 3)];
                oacc[dt] = __builtin_amdgcn_mfma_f32_16x16x32_bf16(pf[kf], vfr, oacc[dt], 0, 0, 0);
            }
        }

        __syncthreads();   // drains my async loads; publishes tile kt+1
    }

    // epilogue: normalize rows q' = 4*g4+r (l gathered from lane 20*g4+r)
    #pragma unroll
    for (int r = 0; r < 4; ++r) {
        float inv = 1.f / __shfl(l, 20*g4 + r);
        size_t row = base + (size_t)(q0 + g4*4 + r)*64;
        #pragma unroll
        for (int dt = 0; dt < 4; ++dt)
            ctx[row + dt*16 + ln] = f2bf(oacc[dt][r] * inv);
    }
}

// ---------------------------------------------------------------------------
// Kernel 3a: convert wo fp32 [1024][1024] -> bf16 tiled
//   wob_t[cb][kt][row][k] = wo[cb*64+row][kt*64+k]   (tile = contiguous 4096)
// ---------------------------------------------------------------------------
__global__ __launch_bounds__(256) void wconv_kernel(
    const float* __restrict__ wo, u16* __restrict__ wob_t)
{
    int g = blockIdx.x*256 + threadIdx.x;   // 131072 slots of 8 elems
    int tile = g >> 9, within = g & 511;
    int row = within >> 3, ks = within & 7;
    int cb = tile >> 4, kt = tile & 15;
    const float* src = &wo[(size_t)(cb*64 + row)*1024 + kt*64 + ks*8];
    float4 a = *(const float4*)src;
    float4 b = *(const float4*)(src + 4);
    u16 o[8];
    o[0]=f2bf(a.x); o[1]=f2bf(a.y); o[2]=f2bf(a.z); o[3]=f2bf(a.w);
    o[4]=f2bf(b.x); o[5]=f2bf(b.y); o[6]=f2bf(b.z); o[7]=f2bf(b.w);
    *(uint4*)&wob_t[(size_t)g*8] = *(uint4*)o;
}

// ---------------------------------------------------------------------------
// Kernel 3b: MFMA output projection.
//   out[m][n] = sum_k A[m][k] * wo[n][k] + bo[n],  M=4096, N=K=1024
// A = ctx workspace reinterpreted as flat row-major [4096][1024] (the
// reference's reshape is a plain flat reshape — round-4 lesson).
// ---------------------------------------------------------------------------
__global__ __launch_bounds__(256) void oproj_kernel(
    const u16* __restrict__ ctx, const u16* __restrict__ wob_t,
    const float* __restrict__ bo, float* __restrict__ out)
{
    __shared__ u16 As[128*64];   // [m][k], swizzled
    __shared__ u16 Bs[64*64];    // [n][k], swizzled
    const int t = threadIdx.x;
    const int wid = t >> 6, lane = t & 63;
    const int ln = lane & 15, g4 = lane >> 4;
    const int wr = wid >> 1, wc = wid & 1;
    const int rb = blockIdx.x, cb = blockIdx.y;
    const int m0 = rb * 128;

    f32x4 acc[4][2];
    #pragma unroll
    for (int mf = 0; mf < 4; ++mf)
        #pragma unroll
        for (int nf = 0; nf < 2; ++nf)
            acc[mf][nf] = (f32x4){0.f, 0.f, 0.f, 0.f};

    for (int kt = 0; kt < 16; ++kt) {
        const u16* bsrc = &wob_t[(size_t)(cb*16 + kt) * 4096];
        __syncthreads();
        #pragma unroll
        for (int c = 0; c < 4; ++c) {
            int sA = t + c*256;                  // 1024 slots of 16B
            int row = sA >> 3, ks = sA & 7;
            *(uint4*)&As[row*64 + ((ks ^ (row & 7)) << 3)] =
                *(const uint4*)&ctx[(size_t)(m0 + row)*1024 + kt*64 + ks*8];
        }
        #pragma unroll
        for (int c = 0; c < 2; ++c) {
            int sB = t + c*256;                  // 512 slots of 16B
            int row = sB >> 3, ks = sB & 7;
            *(uint4*)&Bs[row*64 + ((ks ^ (row & 7)) << 3)] = *(const uint4*)&bsrc[sB*8];
        }
        __syncthreads();

        #pragma unroll
        for (int kf = 0; kf < 2; ++kf) {
            bf16x8 af[4], bfr[2];
            #pragma unroll
            for (int mf = 0; mf < 4; ++mf) {
                int arow = wr*64 + mf*16 + ln;
                af[mf] = *(const bf16x8*)&As[arow*64 + (((kf*4 + g4) ^ (arow & 7)) << 3)];
            }
            #pragma unroll
            for (int nf = 0; nf < 2; ++nf) {
                int brow = wc*32 + nf*16 + ln;
                bfr[nf] = *(const bf16x8*)&Bs[brow*64 + (((kf*4 + g4) ^ (brow & 7)) << 3)];
            }
            #pragma unroll
            for (int mf = 0; mf < 4; ++mf)
                #pragma unroll
                for (int nf = 0; nf < 2; ++nf)
                    acc[mf][nf] = __builtin_amdgcn_mfma_f32_16x16x32_bf16(af[mf], bfr[nf], acc[mf][nf], 0, 0, 0);
        }
    }

    #pragma unroll
    for (int mf = 0; mf < 4; ++mf)
        #pragma unroll
        for (int r = 0; r < 4; ++r) {
            int m = m0 + wr*64 + mf*16 + g4*4 + r;
            #pragma unroll
            for (int nf = 0; nf < 2; ++nf) {
                int col = cb*64 + wc*32 + nf*16 + ln;
                out[(size_t)m*1024 + col] = acc[mf][nf][r] + bo[col];
            }
        }
}

extern "C" void kernel_launch(void* const* d_in, const int* in_sizes, int n_in,
                              void* d_out, int out_size, void* d_ws, size_t ws_size,
                              hipStream_t stream) {
    (void)in_sizes; (void)n_in; (void)out_size; (void)ws_size;
    const float* x  = (const float*)d_in[0];
    const float* wq = (const float*)d_in[1];
    const float* bq = (const float*)d_in[2];
    const float* wk = (const float*)d_in[3];
    const float* bk = (const float*)d_in[4];
    const float* wv = (const float*)d_in[5];
    const float* bv = (const float*)d_in[6];
    const float* wo = (const float*)d_in[7];
    const float* bo = (const float*)d_in[8];
    float* out = (float*)d_out;

    // workspace: Q,K bf16 [65536][64]; Vg bf16 [32][32][64][64]; ctx -> 32 MB
    // After attn_kernel, Q is dead -> its region hosts wob_t (2 MB of 8 MB).
    u16* Qb  = (u16*)d_ws;
    u16* Kb  = Qb + (size_t)NROWS*64;
    u16* Vgb = Kb + (size_t)NROWS*64;
    u16* ctx = Vgb + (size_t)NROWS*64;
    u16* wob_t = Qb;

    qkv_kernel<<<dim3(NROWS/64), 256, 0, stream>>>(x, wq, bq, wk, bk, wv, bv, Qb, Kb, Vgb);
    attn_kernel<<<dim3(32, 32), 256, 0, stream>>>(Qb, Kb, Vgb, ctx);
    wconv_kernel<<<dim3(512), 256, 0, stream>>>(wo, wob_t);
    oproj_kernel<<<dim3(32, 16), 256, 0, stream>>>(ctx, wob_t, bo, out);
}

// Round 8
// 109.529 us; speedup vs baseline: 1.8649x; 1.2252x over previous
//
#include <hip/hip_runtime.h>
#include <hip/hip_bf16.h>

#define SEQ 2048
#define BHCOUNT 32
#define NROWS (BHCOUNT*SEQ)   /* 65536 rows of [64] */

typedef unsigned short u16;
typedef unsigned int u32;
using bf16x8 = __attribute__((ext_vector_type(8))) short;   // 8 bf16 = 4 VGPR
using f32x4  = __attribute__((ext_vector_type(4))) float;

__device__ __forceinline__ float bf2f(u16 h) {
    return __uint_as_float(((u32)h) << 16);
}
__device__ __forceinline__ u16 f2bf(float f) {
    u32 u = __float_as_uint(f);
    u32 r = (u + 0x7FFFu + ((u >> 16) & 1u)) >> 16;
    return (u16)r;
}

// async global->LDS, 16B per lane. Global addr is PER-LANE, LDS dest is
// wave-uniform base + lane*16 (m104). Size must be a literal.
__device__ __forceinline__ void gload16(const u16* g, u16* l) {
    __builtin_amdgcn_global_load_lds(
        (const __attribute__((address_space(1))) u32*)g,
        (__attribute__((address_space(3))) u32*)l, 16, 0, 0);
}

__device__ __forceinline__ void cvt8(const float* src, float sc, u16* o) {
    float4 a = *(const float4*)src;
    float4 b = *(const float4*)(src + 4);
    o[0]=f2bf(a.x*sc); o[1]=f2bf(a.y*sc); o[2]=f2bf(a.z*sc); o[3]=f2bf(a.w*sc);
    o[4]=f2bf(b.x*sc); o[5]=f2bf(b.y*sc); o[6]=f2bf(b.z*sc); o[7]=f2bf(b.w*sc);
}

// ---------------------------------------------------------------------------
// Kernel 1: MFMA QKV projection.  x[65536][64] fp32 ->
//   Q bf16 [65536][64]  (wq/bq pre-scaled by 0.125*log2e: exp2-domain softmax)
//   K bf16 [65536][64]
//   Vg bf16 [32 bh][32 kv-tile][64 d][64 kappa]  (same format as round 5-7:
//     kappa = 32*b0+8*g4+4*b1+r  <->  kv = 16*b0+32*b1+4*g4+r)
// 128 rows/block, 4 waves; x and all three weights staged bf16 in LDS with
// the XOR swizzle; af (x fragments) shared by Q,K (A-side) and V (B-side,
// operand-swapped mfma so V lands transposed for the Vg permute).
// C/D layout (HW-verified): C[A-tile, intra g4*4+r][B-tile, intra ln].
// ---------------------------------------------------------------------------
__global__ __launch_bounds__(256) void qkv_kernel(
    const float* __restrict__ x,
    const float* __restrict__ wq, const float* __restrict__ bq,
    const float* __restrict__ wk, const float* __restrict__ bk,
    const float* __restrict__ wv, const float* __restrict__ bv,
    u16* __restrict__ Q, u16* __restrict__ K, u16* __restrict__ Vg)
{
    __shared__ u16 xs[128*64];   // x tile bf16 swizzled; later vstage[64][128]
    __shared__ u16 ws[192*64];   // wq|wk|wv bf16, swizzled, qscale folded in wq
    __shared__ float bs[192];    // bq*qscale | bk | bv
    const int t = threadIdx.x;
    const int wid = t >> 6, lane = t & 63;
    const int ln = lane & 15, g4 = lane >> 4;
    const int blk = blockIdx.x;
    const int m0 = blk * 128;
    const int bh = blk >> 4;
    const int ktg0 = (blk & 15) * 2;
    const float qscale = 0.125f * 1.44269504f;

    // stage weights fp32->bf16 swizzled (p uniform per chunk c)
    #pragma unroll
    for (int c = 0; c < 6; ++c) {
        int slot = c*256 + t;                // 1536 slots of 8 elems
        int row = slot >> 3, ks = slot & 7;  // row in [0,192)
        const float* wsrc = (c < 2) ? wq : (c < 4) ? wk : wv;
        float sc = (c < 2) ? qscale : 1.f;
        u16 o[8];
        cvt8(&wsrc[(row & 63)*64 + ks*8], sc, o);
        *(uint4*)&ws[row*64 + ((ks ^ (row & 7)) << 3)] = *(uint4*)o;
    }
    // stage x tile fp32->bf16 swizzled
    #pragma unroll
    for (int c = 0; c < 4; ++c) {
        int slot = c*256 + t;                // 1024 slots of 8 elems
        int row = slot >> 3, ks = slot & 7;  // row in [0,128)
        u16 o[8];
        cvt8(&x[(size_t)(m0 + row)*64 + ks*8], 1.f, o);
        *(uint4*)&xs[row*64 + ((ks ^ (row & 7)) << 3)] = *(uint4*)o;
    }
    if (t < 192) {
        int p = t >> 6, e = t & 63;
        bs[t] = (p == 0) ? bq[e]*qscale : (p == 1) ? bk[e] : bv[e];
    }
    __syncthreads();

    // x A-fragments: wave rows wid*32 + mf*16 + ln
    bf16x8 af[2][2];
    #pragma unroll
    for (int mf = 0; mf < 2; ++mf)
        #pragma unroll
        for (int kf = 0; kf < 2; ++kf) {
            int arow = wid*32 + mf*16 + ln;
            af[mf][kf] = *(const bf16x8*)&xs[arow*64 + (((kf*4 + g4) ^ (arow & 7)) << 3)];
        }

    // Q (p=0) and K (p=1):  y[s][e] = sum_d x[s][d]*W[e][d] + b[e]
    #pragma unroll
    for (int p = 0; p < 2; ++p) {
        bf16x8 bfr[4][2];
        #pragma unroll
        for (int nt = 0; nt < 4; ++nt)
            #pragma unroll
            for (int kf = 0; kf < 2; ++kf) {
                int brow = p*64 + nt*16 + ln;
                bfr[nt][kf] = *(const bf16x8*)&ws[brow*64 + (((kf*4 + g4) ^ (ln & 7)) << 3)];
            }
        f32x4 acc[2][4];
        #pragma unroll
        for (int mf = 0; mf < 2; ++mf)
            #pragma unroll
            for (int nt = 0; nt < 4; ++nt) acc[mf][nt] = (f32x4){0.f,0.f,0.f,0.f};
        #pragma unroll
        for (int kf = 0; kf < 2; ++kf)
            #pragma unroll
            for (int mf = 0; mf < 2; ++mf)
                #pragma unroll
                for (int nt = 0; nt < 4; ++nt)
                    acc[mf][nt] = __builtin_amdgcn_mfma_f32_16x16x32_bf16(
                        af[mf][kf], bfr[nt][kf], acc[mf][nt], 0, 0, 0);
        u16* dst = p ? K : Q;
        #pragma unroll
        for (int mf = 0; mf < 2; ++mf)
            #pragma unroll
            for (int nt = 0; nt < 4; ++nt) {
                float bv4 = bs[p*64 + nt*16 + ln];
                #pragma unroll
                for (int r = 0; r < 4; ++r)
                    dst[(size_t)(m0 + wid*32 + mf*16 + g4*4 + r)*64 + nt*16 + ln]
                        = f2bf(acc[mf][nt][r] + bv4);
            }
    }

    // V, operand-swapped: C[e-tile et, intra g4*4+r][s-tile st, intra ln]
    bf16x8 wvf[4][2];
    #pragma unroll
    for (int et = 0; et < 4; ++et)
        #pragma unroll
        for (int kf = 0; kf < 2; ++kf) {
            int brow = 128 + et*16 + ln;
            wvf[et][kf] = *(const bf16x8*)&ws[brow*64 + (((kf*4 + g4) ^ (ln & 7)) << 3)];
        }
    f32x4 vacc[4][2];
    #pragma unroll
    for (int et = 0; et < 4; ++et)
        #pragma unroll
        for (int st = 0; st < 2; ++st) vacc[et][st] = (f32x4){0.f,0.f,0.f,0.f};
    #pragma unroll
    for (int kf = 0; kf < 2; ++kf)
        #pragma unroll
        for (int et = 0; et < 4; ++et)
            #pragma unroll
            for (int st = 0; st < 2; ++st)
                vacc[et][st] = __builtin_amdgcn_mfma_f32_16x16x32_bf16(
                    wvf[et][kf], af[st][kf], vacc[et][st], 0, 0, 0);

    __syncthreads();   // all xs fragment reads done; reuse xs as vstage[64][128]
    u16* vstage = xs;  // row e, column (s + 2e) & 127  (bank-conflict rotation)
    #pragma unroll
    for (int et = 0; et < 4; ++et)
        #pragma unroll
        for (int st = 0; st < 2; ++st)
            #pragma unroll
            for (int r = 0; r < 4; ++r) {
                int e = et*16 + g4*4 + r;
                int s = wid*32 + st*16 + ln;
                vstage[e*128 + ((s + 2*e) & 127)] = f2bf(vacc[et][st][r] + bs[128 + e]);
            }
    __syncthreads();

    // write kappa-permuted tiles: Vg[bh][ktg0+kt2][ee][kp]
    #pragma unroll
    for (int c = 0; c < 8; ++c) {
        int j = c*256 + t;              // 2048 groups of 4 consecutive kappa
        int kt2 = j >> 10, within = j & 1023;
        int ee = within >> 4, kp0 = (within & 15) * 4;
        int sbase = ((kp0 & 4) << 3) | ((kp0 & 32) >> 1) | ((kp0 & 24) >> 1);
        u16 o[4];
        #pragma unroll
        for (int i = 0; i < 4; ++i)
            o[i] = vstage[ee*128 + ((kt2*64 + sbase + i + 2*ee) & 127)];
        *(uint2*)&Vg[((size_t)bh*32 + ktg0 + kt2)*4096 + ee*64 + kp0] = *(uint2*)o;
    }
}

// ---------------------------------------------------------------------------
// Kernel 2: MFMA flash attention, swapped-QK^T, async double-buffered staging.
// (unchanged from round 7 — verified at 85 µs / 805 TF effective)
// ---------------------------------------------------------------------------
__global__ __launch_bounds__(256) void attn_kernel(
    const u16* __restrict__ Q, const u16* __restrict__ K,
    const u16* __restrict__ Vg, u16* __restrict__ ctx)
{
    __shared__ u16 Kls[2][64*64];    // [buf][phys], swizzled via source
    __shared__ u16 Vls[2][64*64];

    const int t = threadIdx.x;
    const int wid = t >> 6, lane = t & 63;
    const int ln = lane & 15, g4 = lane >> 4;
    const int bh = blockIdx.y;
    const size_t base   = (size_t)bh * SEQ * 64;
    const size_t vgbase = (size_t)bh * 32 * 4096;
    const int q0 = blockIdx.x * 64 + wid * 16;

    int goff[2];
    #pragma unroll
    for (int c = 0; c < 2; ++c) {
        int s = wid*128 + c*64 + lane;
        int row = s >> 3, ks = s & 7;
        goff[c] = row*64 + ((ks ^ (row & 7)) << 3);
    }
    const int ldst = wid*128*8;

    bf16x8 qf[2];
    #pragma unroll
    for (int kf = 0; kf < 2; ++kf)
        qf[kf] = *(const bf16x8*)&Q[base + (size_t)(q0 + ln)*64 + kf*32 + g4*8];

    f32x4 oacc[4];
    #pragma unroll
    for (int i = 0; i < 4; ++i) oacc[i] = (f32x4){0.f, 0.f, 0.f, 0.f};
    float m = -1e30f, l = 0.f;

    #pragma unroll
    for (int c = 0; c < 2; ++c) {
        gload16(&K [base   + goff[c]], &Kls[0][ldst + c*512]);
        gload16(&Vg[vgbase + goff[c]], &Vls[0][ldst + c*512]);
    }
    __syncthreads();

    for (int kt = 0; kt < 32; ++kt) {
        const int cur = kt & 1;
        if (kt < 31) {
            const u16* ksrc = &K [base   + (size_t)(kt+1)*4096];
            const u16* vsrc = &Vg[vgbase + (size_t)(kt+1)*4096];
            #pragma unroll
            for (int c = 0; c < 2; ++c) {
                gload16(&ksrc[goff[c]], &Kls[cur^1][ldst + c*512]);
                gload16(&vsrc[goff[c]], &Vls[cur^1][ldst + c*512]);
            }
        }
        const u16* Ks  = Kls[cur];
        const u16* Vts = Vls[cur];

        f32x4 sacc[4];
        #pragma unroll
        for (int nt = 0; nt < 4; ++nt) sacc[nt] = (f32x4){0.f, 0.f, 0.f, 0.f};
        #pragma unroll
        for (int nt = 0; nt < 4; ++nt) {
            #pragma unroll
            for (int kf = 0; kf < 2; ++kf) {
                int krow = nt*16 + ln;
                bf16x8 kfr = *(const bf16x8*)&Ks[krow*64 + (((kf*4 + g4) ^ (krow & 7)) << 3)];
                sacc[nt] = __builtin_amdgcn_mfma_f32_16x16x32_bf16(kfr, qf[kf], sacc[nt], 0, 0, 0);
            }
        }

        float mx = fmaxf(
            fmaxf(fmaxf(fmaxf(sacc[0][0], sacc[0][1]), fmaxf(sacc[0][2], sacc[0][3])),
                  fmaxf(fmaxf(sacc[1][0], sacc[1][1]), fmaxf(sacc[1][2], sacc[1][3]))),
            fmaxf(fmaxf(fmaxf(sacc[2][0], sacc[2][1]), fmaxf(sacc[2][2], sacc[2][3])),
                  fmaxf(fmaxf(sacc[3][0], sacc[3][1]), fmaxf(sacc[3][2], sacc[3][3]))));
        mx = fmaxf(mx, __shfl_xor(mx, 16));
        mx = fmaxf(mx, __shfl_xor(mx, 32));

        float alpha = 1.f;
        if (__any(mx - m > 8.f)) {
            float mn = fmaxf(m, mx);
            alpha = exp2f(m - mn);
            m = mn;
            #pragma unroll
            for (int r = 0; r < 4; ++r) {
                float ar = __shfl(alpha, 20*g4 + r);
                #pragma unroll
                for (int dt = 0; dt < 4; ++dt) oacc[dt][r] *= ar;
            }
        }

        float rs = 0.f;
        #pragma unroll
        for (int nt = 0; nt < 4; ++nt)
            #pragma unroll
            for (int r = 0; r < 4; ++r) {
                sacc[nt][r] = exp2f(sacc[nt][r] - m);
                rs += sacc[nt][r];
            }
        rs += __shfl_xor(rs, 16);
        rs += __shfl_xor(rs, 32);
        l = l*alpha + rs;

        union PU { u32 w[4]; bf16x8 v; } pu0, pu1;
        asm("v_cvt_pk_bf16_f32 %0, %1, %2" : "=v"(pu0.w[0]) : "v"(sacc[0][0]), "v"(sacc[0][1]));
        asm("v_cvt_pk_bf16_f32 %0, %1, %2" : "=v"(pu0.w[1]) : "v"(sacc[0][2]), "v"(sacc[0][3]));
        asm("v_cvt_pk_bf16_f32 %0, %1, %2" : "=v"(pu0.w[2]) : "v"(sacc[2][0]), "v"(sacc[2][1]));
        asm("v_cvt_pk_bf16_f32 %0, %1, %2" : "=v"(pu0.w[3]) : "v"(sacc[2][2]), "v"(sacc[2][3]));
        asm("v_cvt_pk_bf16_f32 %0, %1, %2" : "=v"(pu1.w[0]) : "v"(sacc[1][0]), "v"(sacc[1][1]));
        asm("v_cvt_pk_bf16_f32 %0, %1, %2" : "=v"(pu1.w[1]) : "v"(sacc[1][2]), "v"(sacc[1][3]));
        asm("v_cvt_pk_bf16_f32 %0, %1, %2" : "=v"(pu1.w[2]) : "v"(sacc[3][0]), "v"(sacc[3][1]));
        asm("v_cvt_pk_bf16_f32 %0, %1, %2" : "=v"(pu1.w[3]) : "v"(sacc[3][2]), "v"(sacc[3][3]));
        bf16x8 pf[2] = { pu0.v, pu1.v };

        #pragma unroll
        for (int dt = 0; dt < 4; ++dt) {
            #pragma unroll
            for (int kf = 0; kf < 2; ++kf) {
                int vrow = dt*16 + ln;
                bf16x8 vfr = *(const bf16x8*)&Vts[vrow*64 + (((kf*4 + g4) ^ (vrow & 7)) << 3)];
                oacc[dt] = __builtin_amdgcn_mfma_f32_16x16x32_bf16(pf[kf], vfr, oacc[dt], 0, 0, 0);
            }
        }

        __syncthreads();
    }

    #pragma unroll
    for (int r = 0; r < 4; ++r) {
        float inv = 1.f / __shfl(l, 20*g4 + r);
        size_t row = base + (size_t)(q0 + g4*4 + r)*64;
        #pragma unroll
        for (int dt = 0; dt < 4; ++dt)
            ctx[row + dt*16 + ln] = f2bf(oacc[dt][r] * inv);
    }
}

// ---------------------------------------------------------------------------
// Kernel 3a: convert wo fp32 [1024][1024] -> bf16 tiled
// ---------------------------------------------------------------------------
__global__ __launch_bounds__(256) void wconv_kernel(
    const float* __restrict__ wo, u16* __restrict__ wob_t)
{
    int g = blockIdx.x*256 + threadIdx.x;   // 131072 slots of 8 elems
    int tile = g >> 9, within = g & 511;
    int row = within >> 3, ks = within & 7;
    int cb = tile >> 4, kt = tile & 15;
    u16 o[8];
    cvt8(&wo[(size_t)(cb*64 + row)*1024 + kt*64 + ks*8], 1.f, o);
    *(uint4*)&wob_t[(size_t)g*8] = *(uint4*)o;
}

// ---------------------------------------------------------------------------
// Kernel 3b: MFMA output projection (flat-reshape A — round-4 lesson).
// ---------------------------------------------------------------------------
__global__ __launch_bounds__(256) void oproj_kernel(
    const u16* __restrict__ ctx, const u16* __restrict__ wob_t,
    const float* __restrict__ bo, float* __restrict__ out)
{
    __shared__ u16 As[128*64];   // [m][k], swizzled
    __shared__ u16 Bs[64*64];    // [n][k], swizzled
    const int t = threadIdx.x;
    const int wid = t >> 6, lane = t & 63;
    const int ln = lane & 15, g4 = lane >> 4;
    const int wr = wid >> 1, wc = wid & 1;
    const int rb = blockIdx.x, cb = blockIdx.y;
    const int m0 = rb * 128;

    f32x4 acc[4][2];
    #pragma unroll
    for (int mf = 0; mf < 4; ++mf)
        #pragma unroll
        for (int nf = 0; nf < 2; ++nf)
            acc[mf][nf] = (f32x4){0.f, 0.f, 0.f, 0.f};

    for (int kt = 0; kt < 16; ++kt) {
        const u16* bsrc = &wob_t[(size_t)(cb*16 + kt) * 4096];
        __syncthreads();
        #pragma unroll
        for (int c = 0; c < 4; ++c) {
            int sA = t + c*256;                  // 1024 slots of 16B
            int row = sA >> 3, ks = sA & 7;
            *(uint4*)&As[row*64 + ((ks ^ (row & 7)) << 3)] =
                *(const uint4*)&ctx[(size_t)(m0 + row)*1024 + kt*64 + ks*8];
        }
        #pragma unroll
        for (int c = 0; c < 2; ++c) {
            int sB = t + c*256;                  // 512 slots of 16B
            int row = sB >> 3, ks = sB & 7;
            *(uint4*)&Bs[row*64 + ((ks ^ (row & 7)) << 3)] = *(const uint4*)&bsrc[sB*8];
        }
        __syncthreads();

        #pragma unroll
        for (int kf = 0; kf < 2; ++kf) {
            bf16x8 af[4], bfr[2];
            #pragma unroll
            for (int mf = 0; mf < 4; ++mf) {
                int arow = wr*64 + mf*16 + ln;
                af[mf] = *(const bf16x8*)&As[arow*64 + (((kf*4 + g4) ^ (arow & 7)) << 3)];
            }
            #pragma unroll
            for (int nf = 0; nf < 2; ++nf) {
                int brow = wc*32 + nf*16 + ln;
                bfr[nf] = *(const bf16x8*)&Bs[brow*64 + (((kf*4 + g4) ^ (brow & 7)) << 3)];
            }
            #pragma unroll
            for (int mf = 0; mf < 4; ++mf)
                #pragma unroll
                for (int nf = 0; nf < 2; ++nf)
                    acc[mf][nf] = __builtin_amdgcn_mfma_f32_16x16x32_bf16(af[mf], bfr[nf], acc[mf][nf], 0, 0, 0);
        }
    }

    #pragma unroll
    for (int mf = 0; mf < 4; ++mf)
        #pragma unroll
        for (int r = 0; r < 4; ++r) {
            int m = m0 + wr*64 + mf*16 + g4*4 + r;
            #pragma unroll
            for (int nf = 0; nf < 2; ++nf) {
                int col = cb*64 + wc*32 + nf*16 + ln;
                out[(size_t)m*1024 + col] = acc[mf][nf][r] + bo[col];
            }
        }
}

extern "C" void kernel_launch(void* const* d_in, const int* in_sizes, int n_in,
                              void* d_out, int out_size, void* d_ws, size_t ws_size,
                              hipStream_t stream) {
    (void)in_sizes; (void)n_in; (void)out_size; (void)ws_size;
    const float* x  = (const float*)d_in[0];
    const float* wq = (const float*)d_in[1];
    const float* bq = (const float*)d_in[2];
    const float* wk = (const float*)d_in[3];
    const float* bk = (const float*)d_in[4];
    const float* wv = (const float*)d_in[5];
    const float* bv = (const float*)d_in[6];
    const float* wo = (const float*)d_in[7];
    const float* bo = (const float*)d_in[8];
    float* out = (float*)d_out;

    // workspace: Q,K bf16 [65536][64]; Vg bf16 [32][32][64][64]; ctx -> 32 MB
    // After attn_kernel, Q is dead -> its region hosts wob_t (2 MB of 8 MB).
    u16* Qb  = (u16*)d_ws;
    u16* Kb  = Qb + (size_t)NROWS*64;
    u16* Vgb = Kb + (size_t)NROWS*64;
    u16* ctx = Vgb + (size_t)NROWS*64;
    u16* wob_t = Qb;

    qkv_kernel<<<dim3(NROWS/128), 256, 0, stream>>>(x, wq, bq, wk, bk, wv, bv, Qb, Kb, Vgb);
    attn_kernel<<<dim3(32, 32), 256, 0, stream>>>(Qb, Kb, Vgb, ctx);
    wconv_kernel<<<dim3(512), 256, 0, stream>>>(wo, wob_t);
    oproj_kernel<<<dim3(32, 16), 256, 0, stream>>>(ctx, wob_t, bo, out);
}

// Round 9
// 84.791 us; speedup vs baseline: 2.4090x; 1.2917x over previous
//
#include <hip/hip_runtime.h>
#include <hip/hip_bf16.h>

#define SEQ 2048
#define BHCOUNT 32
#define NROWS (BHCOUNT*SEQ)   /* 65536 rows of [64] */

typedef unsigned short u16;
typedef unsigned int u32;
using bf16x8 = __attribute__((ext_vector_type(8))) short;   // 8 bf16 = 4 VGPR
using f32x4  = __attribute__((ext_vector_type(4))) float;

__device__ __forceinline__ float bf2f(u16 h) {
    return __uint_as_float(((u32)h) << 16);
}
__device__ __forceinline__ u16 f2bf(float f) {
    u32 u = __float_as_uint(f);
    u32 r = (u + 0x7FFFu + ((u >> 16) & 1u)) >> 16;
    return (u16)r;
}
// raw v_exp_f32 (2^x). Flushes tiny results to 0 — fine for softmax tails.
__device__ __forceinline__ float fexp2(float x) {
    float r; asm("v_exp_f32 %0, %1" : "=v"(r) : "v"(x)); return r;
}

// async global->LDS, 16B per lane. Global addr is PER-LANE, LDS dest is
// wave-uniform base + lane*16 (m104). Size must be a literal.
__device__ __forceinline__ void gload16(const u16* g, u16* l) {
    __builtin_amdgcn_global_load_lds(
        (const __attribute__((address_space(1))) u32*)g,
        (__attribute__((address_space(3))) u32*)l, 16, 0, 0);
}

__device__ __forceinline__ void cvt8(const float* src, float sc, u16* o) {
    float4 a = *(const float4*)src;
    float4 b = *(const float4*)(src + 4);
    o[0]=f2bf(a.x*sc); o[1]=f2bf(a.y*sc); o[2]=f2bf(a.z*sc); o[3]=f2bf(a.w*sc);
    o[4]=f2bf(b.x*sc); o[5]=f2bf(b.y*sc); o[6]=f2bf(b.z*sc); o[7]=f2bf(b.w*sc);
}

// ---------------------------------------------------------------------------
// Kernel 1: MFMA QKV projection (unchanged from round 8 — verified).
// ---------------------------------------------------------------------------
__global__ __launch_bounds__(256) void qkv_kernel(
    const float* __restrict__ x,
    const float* __restrict__ wq, const float* __restrict__ bq,
    const float* __restrict__ wk, const float* __restrict__ bk,
    const float* __restrict__ wv, const float* __restrict__ bv,
    u16* __restrict__ Q, u16* __restrict__ K, u16* __restrict__ Vg)
{
    __shared__ u16 xs[128*64];   // x tile bf16 swizzled; later vstage[64][128]
    __shared__ u16 ws[192*64];   // wq|wk|wv bf16, swizzled, qscale folded in wq
    __shared__ float bs[192];    // bq*qscale | bk | bv
    const int t = threadIdx.x;
    const int wid = t >> 6, lane = t & 63;
    const int ln = lane & 15, g4 = lane >> 4;
    const int blk = blockIdx.x;
    const int m0 = blk * 128;
    const int bh = blk >> 4;
    const int ktg0 = (blk & 15) * 2;
    const float qscale = 0.125f * 1.44269504f;

    #pragma unroll
    for (int c = 0; c < 6; ++c) {
        int slot = c*256 + t;
        int row = slot >> 3, ks = slot & 7;
        const float* wsrc = (c < 2) ? wq : (c < 4) ? wk : wv;
        float sc = (c < 2) ? qscale : 1.f;
        u16 o[8];
        cvt8(&wsrc[(row & 63)*64 + ks*8], sc, o);
        *(uint4*)&ws[row*64 + ((ks ^ (row & 7)) << 3)] = *(uint4*)o;
    }
    #pragma unroll
    for (int c = 0; c < 4; ++c) {
        int slot = c*256 + t;
        int row = slot >> 3, ks = slot & 7;
        u16 o[8];
        cvt8(&x[(size_t)(m0 + row)*64 + ks*8], 1.f, o);
        *(uint4*)&xs[row*64 + ((ks ^ (row & 7)) << 3)] = *(uint4*)o;
    }
    if (t < 192) {
        int p = t >> 6, e = t & 63;
        bs[t] = (p == 0) ? bq[e]*qscale : (p == 1) ? bk[e] : bv[e];
    }
    __syncthreads();

    bf16x8 af[2][2];
    #pragma unroll
    for (int mf = 0; mf < 2; ++mf)
        #pragma unroll
        for (int kf = 0; kf < 2; ++kf) {
            int arow = wid*32 + mf*16 + ln;
            af[mf][kf] = *(const bf16x8*)&xs[arow*64 + (((kf*4 + g4) ^ (arow & 7)) << 3)];
        }

    #pragma unroll
    for (int p = 0; p < 2; ++p) {
        bf16x8 bfr[4][2];
        #pragma unroll
        for (int nt = 0; nt < 4; ++nt)
            #pragma unroll
            for (int kf = 0; kf < 2; ++kf) {
                int brow = p*64 + nt*16 + ln;
                bfr[nt][kf] = *(const bf16x8*)&ws[brow*64 + (((kf*4 + g4) ^ (ln & 7)) << 3)];
            }
        f32x4 acc[2][4];
        #pragma unroll
        for (int mf = 0; mf < 2; ++mf)
            #pragma unroll
            for (int nt = 0; nt < 4; ++nt) acc[mf][nt] = (f32x4){0.f,0.f,0.f,0.f};
        #pragma unroll
        for (int kf = 0; kf < 2; ++kf)
            #pragma unroll
            for (int mf = 0; mf < 2; ++mf)
                #pragma unroll
                for (int nt = 0; nt < 4; ++nt)
                    acc[mf][nt] = __builtin_amdgcn_mfma_f32_16x16x32_bf16(
                        af[mf][kf], bfr[nt][kf], acc[mf][nt], 0, 0, 0);
        u16* dst = p ? K : Q;
        #pragma unroll
        for (int mf = 0; mf < 2; ++mf)
            #pragma unroll
            for (int nt = 0; nt < 4; ++nt) {
                float bv4 = bs[p*64 + nt*16 + ln];
                #pragma unroll
                for (int r = 0; r < 4; ++r)
                    dst[(size_t)(m0 + wid*32 + mf*16 + g4*4 + r)*64 + nt*16 + ln]
                        = f2bf(acc[mf][nt][r] + bv4);
            }
    }

    bf16x8 wvf[4][2];
    #pragma unroll
    for (int et = 0; et < 4; ++et)
        #pragma unroll
        for (int kf = 0; kf < 2; ++kf) {
            int brow = 128 + et*16 + ln;
            wvf[et][kf] = *(const bf16x8*)&ws[brow*64 + (((kf*4 + g4) ^ (ln & 7)) << 3)];
        }
    f32x4 vacc[4][2];
    #pragma unroll
    for (int et = 0; et < 4; ++et)
        #pragma unroll
        for (int st = 0; st < 2; ++st) vacc[et][st] = (f32x4){0.f,0.f,0.f,0.f};
    #pragma unroll
    for (int kf = 0; kf < 2; ++kf)
        #pragma unroll
        for (int et = 0; et < 4; ++et)
            #pragma unroll
            for (int st = 0; st < 2; ++st)
                vacc[et][st] = __builtin_amdgcn_mfma_f32_16x16x32_bf16(
                    wvf[et][kf], af[st][kf], vacc[et][st], 0, 0, 0);

    __syncthreads();
    u16* vstage = xs;
    #pragma unroll
    for (int et = 0; et < 4; ++et)
        #pragma unroll
        for (int st = 0; st < 2; ++st)
            #pragma unroll
            for (int r = 0; r < 4; ++r) {
                int e = et*16 + g4*4 + r;
                int s = wid*32 + st*16 + ln;
                vstage[e*128 + ((s + 2*e) & 127)] = f2bf(vacc[et][st][r] + bs[128 + e]);
            }
    __syncthreads();

    #pragma unroll
    for (int c = 0; c < 8; ++c) {
        int j = c*256 + t;
        int kt2 = j >> 10, within = j & 1023;
        int ee = within >> 4, kp0 = (within & 15) * 4;
        int sbase = ((kp0 & 4) << 3) | ((kp0 & 32) >> 1) | ((kp0 & 24) >> 1);
        u16 o[4];
        #pragma unroll
        for (int i = 0; i < 4; ++i)
            o[i] = vstage[ee*128 + ((kt2*64 + sbase + i + 2*ee) & 127)];
        *(uint2*)&Vg[((size_t)bh*32 + ktg0 + kt2)*4096 + ee*64 + kp0] = *(uint2*)o;
    }
}

// ---------------------------------------------------------------------------
// Kernel 2: MFMA flash attention, swapped-QK^T, async double-buffered staging.
// Round 9: 8 waves (512 thr), 128 q-rows/block -> K/V staging amortized 2x;
// grid (16,32). LDS frag-read offsets hoisted (koff==voff formula); kt loop
// unrolled 2x so the buffer index is compile-time; raw v_exp_f32 for exp2;
// s_setprio(1) around both MFMA clusters (T5).
// All fragment math identical to rounds 7-8 (verified).
// ---------------------------------------------------------------------------
__global__ __launch_bounds__(512) void attn_kernel(
    const u16* __restrict__ Q, const u16* __restrict__ K,
    const u16* __restrict__ Vg, u16* __restrict__ ctx)
{
    __shared__ u16 Kls[2][4096];    // [buf][phys], swizzled via source
    __shared__ u16 Vls[2][4096];

    const int t = threadIdx.x;
    const int wid = t >> 6, lane = t & 63;
    const int ln = lane & 15, g4 = lane >> 4;
    const int bh = blockIdx.y;
    const size_t base   = (size_t)bh * SEQ * 64;
    const size_t vgbase = (size_t)bh * 32 * 4096;
    const int q0 = blockIdx.x * 128 + wid * 16;

    // staging: 512 slots of 16B per 64x64 tile; lane t stages slot t.
    int goff;
    {
        int row = t >> 3, ks = t & 7;
        goff = row*64 + ((ks ^ (row & 7)) << 3);
    }
    const int ldst = wid * 512;   // element offset of wave's LDS dest region

    // hoisted fragment-read offsets (same formula for K and V reads)
    int foff[4][2];
    #pragma unroll
    for (int nt = 0; nt < 4; ++nt)
        #pragma unroll
        for (int kf = 0; kf < 2; ++kf) {
            int frow = nt*16 + ln;
            foff[nt][kf] = frow*64 + (((kf*4 + g4) ^ (frow & 7)) << 3);
        }

    // Q fragments (B-operand of swapped QK^T)
    bf16x8 qf[2];
    #pragma unroll
    for (int kf = 0; kf < 2; ++kf)
        qf[kf] = *(const bf16x8*)&Q[base + (size_t)(q0 + ln)*64 + kf*32 + g4*8];

    f32x4 oacc[4];
    #pragma unroll
    for (int i = 0; i < 4; ++i) oacc[i] = (f32x4){0.f, 0.f, 0.f, 0.f};
    float m = -1e30f, l = 0.f;

    // prologue: stage tile 0 into buf 0; set up incremental next-tile ptrs
    gload16(&K [base   + goff], &Kls[0][ldst]);
    gload16(&Vg[vgbase + goff], &Vls[0][ldst]);
    const u16* kptr = &K [base   + 4096 + goff];
    const u16* vptr = &Vg[vgbase + 4096 + goff];
    __syncthreads();

    for (int kt2 = 0; kt2 < 16; ++kt2) {
        #pragma unroll
        for (int half = 0; half < 2; ++half) {
            const int kt = kt2*2 + half;
            if (kt < 31) {
                gload16(kptr, &Kls[half^1][ldst]);
                gload16(vptr, &Vls[half^1][ldst]);
                kptr += 4096; vptr += 4096;
            }
            const u16* Ks  = Kls[half];
            const u16* Vts = Vls[half];

            // S^T tiles: sacc[nt] = K_tile(nt) · Q^T
            f32x4 sacc[4];
            #pragma unroll
            for (int nt = 0; nt < 4; ++nt) sacc[nt] = (f32x4){0.f, 0.f, 0.f, 0.f};
            __builtin_amdgcn_s_setprio(1);
            #pragma unroll
            for (int nt = 0; nt < 4; ++nt)
                #pragma unroll
                for (int kf = 0; kf < 2; ++kf)
                    sacc[nt] = __builtin_amdgcn_mfma_f32_16x16x32_bf16(
                        *(const bf16x8*)&Ks[foff[nt][kf]], qf[kf], sacc[nt], 0, 0, 0);
            __builtin_amdgcn_s_setprio(0);

            // lane-local online softmax for q = ln
            float mx = fmaxf(
                fmaxf(fmaxf(fmaxf(sacc[0][0], sacc[0][1]), fmaxf(sacc[0][2], sacc[0][3])),
                      fmaxf(fmaxf(sacc[1][0], sacc[1][1]), fmaxf(sacc[1][2], sacc[1][3]))),
                fmaxf(fmaxf(fmaxf(sacc[2][0], sacc[2][1]), fmaxf(sacc[2][2], sacc[2][3])),
                      fmaxf(fmaxf(sacc[3][0], sacc[3][1]), fmaxf(sacc[3][2], sacc[3][3]))));
            mx = fmaxf(mx, __shfl_xor(mx, 16));
            mx = fmaxf(mx, __shfl_xor(mx, 32));

            float alpha = 1.f;
            if (__any(mx - m > 8.f)) {          // defer-max (T13)
                float mn = fmaxf(m, mx);
                alpha = fexp2(m - mn);
                m = mn;
                #pragma unroll
                for (int r = 0; r < 4; ++r) {
                    float ar = __shfl(alpha, 20*g4 + r);
                    #pragma unroll
                    for (int dt = 0; dt < 4; ++dt) oacc[dt][r] *= ar;
                }
            }

            float rs = 0.f;
            #pragma unroll
            for (int nt = 0; nt < 4; ++nt)
                #pragma unroll
                for (int r = 0; r < 4; ++r) {
                    sacc[nt][r] = fexp2(sacc[nt][r] - m);
                    rs += sacc[nt][r];
                }
            rs += __shfl_xor(rs, 16);
            rs += __shfl_xor(rs, 32);
            l = l*alpha + rs;

            union PU { u32 w[4]; bf16x8 v; } pu0, pu1;
            asm("v_cvt_pk_bf16_f32 %0, %1, %2" : "=v"(pu0.w[0]) : "v"(sacc[0][0]), "v"(sacc[0][1]));
            asm("v_cvt_pk_bf16_f32 %0, %1, %2" : "=v"(pu0.w[1]) : "v"(sacc[0][2]), "v"(sacc[0][3]));
            asm("v_cvt_pk_bf16_f32 %0, %1, %2" : "=v"(pu0.w[2]) : "v"(sacc[2][0]), "v"(sacc[2][1]));
            asm("v_cvt_pk_bf16_f32 %0, %1, %2" : "=v"(pu0.w[3]) : "v"(sacc[2][2]), "v"(sacc[2][3]));
            asm("v_cvt_pk_bf16_f32 %0, %1, %2" : "=v"(pu1.w[0]) : "v"(sacc[1][0]), "v"(sacc[1][1]));
            asm("v_cvt_pk_bf16_f32 %0, %1, %2" : "=v"(pu1.w[1]) : "v"(sacc[1][2]), "v"(sacc[1][3]));
            asm("v_cvt_pk_bf16_f32 %0, %1, %2" : "=v"(pu1.w[2]) : "v"(sacc[3][0]), "v"(sacc[3][1]));
            asm("v_cvt_pk_bf16_f32 %0, %1, %2" : "=v"(pu1.w[3]) : "v"(sacc[3][2]), "v"(sacc[3][3]));
            bf16x8 pf[2] = { pu0.v, pu1.v };

            // O += P · V'
            __builtin_amdgcn_s_setprio(1);
            #pragma unroll
            for (int dt = 0; dt < 4; ++dt)
                #pragma unroll
                for (int kf = 0; kf < 2; ++kf)
                    oacc[dt] = __builtin_amdgcn_mfma_f32_16x16x32_bf16(
                        pf[kf], *(const bf16x8*)&Vts[foff[dt][kf]], oacc[dt], 0, 0, 0);
            __builtin_amdgcn_s_setprio(0);

            __syncthreads();   // drains my async loads; publishes tile kt+1
        }
    }

    // epilogue: normalize rows q' = 4*g4+r (l gathered from lane 20*g4+r)
    #pragma unroll
    for (int r = 0; r < 4; ++r) {
        float inv = 1.f / __shfl(l, 20*g4 + r);
        size_t row = base + (size_t)(q0 + g4*4 + r)*64;
        #pragma unroll
        for (int dt = 0; dt < 4; ++dt)
            ctx[row + dt*16 + ln] = f2bf(oacc[dt][r] * inv);
    }
}

// ---------------------------------------------------------------------------
// Kernel 3a: convert wo fp32 [1024][1024] -> bf16 tiled
// ---------------------------------------------------------------------------
__global__ __launch_bounds__(256) void wconv_kernel(
    const float* __restrict__ wo, u16* __restrict__ wob_t)
{
    int g = blockIdx.x*256 + threadIdx.x;
    int tile = g >> 9, within = g & 511;
    int row = within >> 3, ks = within & 7;
    int cb = tile >> 4, kt = tile & 15;
    u16 o[8];
    cvt8(&wo[(size_t)(cb*64 + row)*1024 + kt*64 + ks*8], 1.f, o);
    *(uint4*)&wob_t[(size_t)g*8] = *(uint4*)o;
}

// ---------------------------------------------------------------------------
// Kernel 3b: MFMA output projection (flat-reshape A — round-4 lesson).
// ---------------------------------------------------------------------------
__global__ __launch_bounds__(256) void oproj_kernel(
    const u16* __restrict__ ctx, const u16* __restrict__ wob_t,
    const float* __restrict__ bo, float* __restrict__ out)
{
    __shared__ u16 As[128*64];   // [m][k], swizzled
    __shared__ u16 Bs[64*64];    // [n][k], swizzled
    const int t = threadIdx.x;
    const int wid = t >> 6, lane = t & 63;
    const int ln = lane & 15, g4 = lane >> 4;
    const int wr = wid >> 1, wc = wid & 1;
    const int rb = blockIdx.x, cb = blockIdx.y;
    const int m0 = rb * 128;

    f32x4 acc[4][2];
    #pragma unroll
    for (int mf = 0; mf < 4; ++mf)
        #pragma unroll
        for (int nf = 0; nf < 2; ++nf)
            acc[mf][nf] = (f32x4){0.f, 0.f, 0.f, 0.f};

    for (int kt = 0; kt < 16; ++kt) {
        const u16* bsrc = &wob_t[(size_t)(cb*16 + kt) * 4096];
        __syncthreads();
        #pragma unroll
        for (int c = 0; c < 4; ++c) {
            int sA = t + c*256;
            int row = sA >> 3, ks = sA & 7;
            *(uint4*)&As[row*64 + ((ks ^ (row & 7)) << 3)] =
                *(const uint4*)&ctx[(size_t)(m0 + row)*1024 + kt*64 + ks*8];
        }
        #pragma unroll
        for (int c = 0; c < 2; ++c) {
            int sB = t + c*256;
            int row = sB >> 3, ks = sB & 7;
            *(uint4*)&Bs[row*64 + ((ks ^ (row & 7)) << 3)] = *(const uint4*)&bsrc[sB*8];
        }
        __syncthreads();

        #pragma unroll
        for (int kf = 0; kf < 2; ++kf) {
            bf16x8 af[4], bfr[2];
            #pragma unroll
            for (int mf = 0; mf < 4; ++mf) {
                int arow = wr*64 + mf*16 + ln;
                af[mf] = *(const bf16x8*)&As[arow*64 + (((kf*4 + g4) ^ (arow & 7)) << 3)];
            }
            #pragma unroll
            for (int nf = 0; nf < 2; ++nf) {
                int brow = wc*32 + nf*16 + ln;
                bfr[nf] = *(const bf16x8*)&Bs[brow*64 + (((kf*4 + g4) ^ (brow & 7)) << 3)];
            }
            #pragma unroll
            for (int mf = 0; mf < 4; ++mf)
                #pragma unroll
                for (int nf = 0; nf < 2; ++nf)
                    acc[mf][nf] = __builtin_amdgcn_mfma_f32_16x16x32_bf16(af[mf], bfr[nf], acc[mf][nf], 0, 0, 0);
        }
    }

    #pragma unroll
    for (int mf = 0; mf < 4; ++mf)
        #pragma unroll
        for (int r = 0; r < 4; ++r) {
            int m = m0 + wr*64 + mf*16 + g4*4 + r;
            #pragma unroll
            for (int nf = 0; nf < 2; ++nf) {
                int col = cb*64 + wc*32 + nf*16 + ln;
                out[(size_t)m*1024 + col] = acc[mf][nf][r] + bo[col];
            }
        }
}

extern "C" void kernel_launch(void* const* d_in, const int* in_sizes, int n_in,
                              void* d_out, int out_size, void* d_ws, size_t ws_size,
                              hipStream_t stream) {
    (void)in_sizes; (void)n_in; (void)out_size; (void)ws_size;
    const float* x  = (const float*)d_in[0];
    const float* wq = (const float*)d_in[1];
    const float* bq = (const float*)d_in[2];
    const float* wk = (const float*)d_in[3];
    const float* bk = (const float*)d_in[4];
    const float* wv = (const float*)d_in[5];
    const float* bv = (const float*)d_in[6];
    const float* wo = (const float*)d_in[7];
    const float* bo = (const float*)d_in[8];
    float* out = (float*)d_out;

    u16* Qb  = (u16*)d_ws;
    u16* Kb  = Qb + (size_t)NROWS*64;
    u16* Vgb = Kb + (size_t)NROWS*64;
    u16* ctx = Vgb + (size_t)NROWS*64;
    u16* wob_t = Qb;

    qkv_kernel<<<dim3(NROWS/128), 256, 0, stream>>>(x, wq, bq, wk, bk, wv, bv, Qb, Kb, Vgb);
    attn_kernel<<<dim3(16, 32), 512, 0, stream>>>(Qb, Kb, Vgb, ctx);
    wconv_kernel<<<dim3(512), 256, 0, stream>>>(wo, wob_t);
    oproj_kernel<<<dim3(32, 16), 256, 0, stream>>>(ctx, wob_t, bo, out);
}